// Round 1
// baseline (922.510 us; speedup 1.0000x reference)
//
#include <hip/hip_runtime.h>

#define B_    4096
#define P_    64
#define OBS_  128
#define HID_  256
#define ACTD_ 32

typedef __attribute__((ext_vector_type(8))) __bf16 bf16x8;
typedef __attribute__((ext_vector_type(4))) float  f32x4;

#define XSTRIDE 264   // X LDS row stride in bf16 elems (528 B: 16B-aligned, bank-staggered)
#define WSTRIDE 40    // Wt LDS row stride in bf16 elems (80 B: 16B-aligned, bank-staggered)

__device__ __forceinline__ unsigned short f2bf(float x) {
    unsigned u = __builtin_bit_cast(unsigned, x);
    u = (u + 0x7fffu + ((u >> 16) & 1u)) >> 16;   // round-to-nearest-even
    return (unsigned short)u;
}

// One fused layer: Y = GN(Xin @ W + b) * g + be, optional ELU.
// Xin: LDS bf16 [128][XSTRIDE]; W global fp32 [P][K][N]; output -> LDS bf16 or global fp32.
template<int NT, int KCH, bool ELU, bool TO_GLOBAL>
__device__ __forceinline__ void layer_fwd(
    const unsigned short* __restrict__ Xin,
    unsigned short* __restrict__ Xout,
    unsigned short* __restrict__ Wt,
    const float* __restrict__ Wg,
    const float* __restrict__ bg,
    const float* __restrict__ gg,
    const float* __restrict__ beg,
    int p, int tid, int wave, int ln, int q,
    float* __restrict__ outg, int bbase)
{
    constexpr int N = NT * 16;
    constexpr int K = KCH * 32;

    f32x4 acc[NT];
#pragma unroll
    for (int nt = 0; nt < NT; ++nt) acc[nt] = (f32x4){0.f, 0.f, 0.f, 0.f};

    const float* Wp = Wg + (long)p * (K * N);

    for (int c = 0; c < KCH; ++c) {
        __syncthreads();   // prev chunk fully consumed before overwriting Wt
        // stage chunk c: global fp32 [32][N] -> LDS bf16 transposed [N][32]
        const float* Wc = Wp + c * 32 * N;
        constexpr int PAIRS = N * 16;   // (n, k-pair) items
        for (int idx = tid; idx < PAIRS; idx += 512) {
            int n  = idx & (N - 1);
            int kp = idx / N;           // k-pair 0..15
            float w0 = Wc[(2 * kp) * N + n];
            float w1 = Wc[(2 * kp + 1) * N + n];
            unsigned pk = (unsigned)f2bf(w0) | ((unsigned)f2bf(w1) << 16);
            *reinterpret_cast<unsigned*>(Wt + n * WSTRIDE + kp * 2) = pk;
        }
        __syncthreads();

        // A-frag: X[m=ln][k = c*32 + q*8 + j]  (one ds_read_b128)
        bf16x8 a = *reinterpret_cast<const bf16x8*>(
            Xin + (wave * 16 + ln) * XSTRIDE + c * 32 + q * 8);
#pragma unroll
        for (int nt = 0; nt < NT; ++nt) {
            // B-frag: W[k][n=nt*16+ln] from transposed LDS (one ds_read_b128)
            bf16x8 b = *reinterpret_cast<const bf16x8*>(
                Wt + (nt * 16 + ln) * WSTRIDE + q * 8);
            acc[nt] = __builtin_amdgcn_mfma_f32_16x16x32_bf16(a, b, acc[nt], 0, 0, 0);
        }
    }

    // ---- epilogue: bias + GroupNorm(+ELU) in fp32 ----
    const float* bp  = bg  + p * N;
    const float* gp  = gg  + p * N;
    const float* bep = beg + p * N;

#pragma unroll
    for (int nt = 0; nt < NT; ++nt) {
        float bias = bp[nt * 16 + ln];
#pragma unroll
        for (int r = 0; r < 4; ++r) acc[nt][r] += bias;
    }

    // per-row (row = q*4 + r) stats: tile-local sum, then butterfly over the 16 lanes of the quad
    float mu[4], rs[4];
#pragma unroll
    for (int r = 0; r < 4; ++r) {
        float s = 0.f, s2 = 0.f;
#pragma unroll
        for (int nt = 0; nt < NT; ++nt) { float v = acc[nt][r]; s += v; s2 += v * v; }
        s += __shfl_xor(s, 1);  s2 += __shfl_xor(s2, 1);
        s += __shfl_xor(s, 2);  s2 += __shfl_xor(s2, 2);
        s += __shfl_xor(s, 4);  s2 += __shfl_xor(s2, 4);
        s += __shfl_xor(s, 8);  s2 += __shfl_xor(s2, 8);
        float m   = s * (1.f / N);
        float var = s2 * (1.f / N) - m * m;
        mu[r] = m;
        rs[r] = rsqrtf(var + 1e-5f);
    }

#pragma unroll
    for (int nt = 0; nt < NT; ++nt) {
        int n = nt * 16 + ln;
        float gv = gp[n], bev = bep[n];
#pragma unroll
        for (int r = 0; r < 4; ++r) {
            float v = (acc[nt][r] - mu[r]) * rs[r] * gv + bev;
            if (ELU) v = (v > 0.f) ? v : expm1f(v);
            if (TO_GLOBAL) {
                int row = bbase + wave * 16 + q * 4 + r;
                outg[((long)row * P_ + p) * ACTD_ + n] = v;
            } else {
                Xout[(wave * 16 + q * 4 + r) * XSTRIDE + n] = f2bf(v);
            }
        }
    }
}

extern "C" __global__ void __launch_bounds__(512, 2)
policy_fused(const float* __restrict__ obs,
             const float* __restrict__ W1, const float* __restrict__ b1,
             const float* __restrict__ g1, const float* __restrict__ be1,
             const float* __restrict__ W2, const float* __restrict__ b2,
             const float* __restrict__ g2, const float* __restrict__ be2,
             const float* __restrict__ W3, const float* __restrict__ b3,
             const float* __restrict__ g3, const float* __restrict__ be3,
             const float* __restrict__ W4, const float* __restrict__ b4,
             const float* __restrict__ g4, const float* __restrict__ be4,
             float* __restrict__ out)
{
    __shared__ __align__(16) unsigned short Xa[128 * XSTRIDE];
    __shared__ __align__(16) unsigned short Xb[128 * XSTRIDE];
    __shared__ __align__(16) unsigned short Wt[256 * WSTRIDE];

    const int tid  = threadIdx.x;
    const int wave = tid >> 6;
    const int lane = tid & 63;
    const int ln   = lane & 15;
    const int q    = lane >> 4;
    const int bx   = blockIdx.x;
    const int p     = bx >> 5;          // 32 consecutive blocks share a policy (L2/LLC reuse)
    const int bbase = (bx & 31) * 128;  // batch-tile base row

    // stage observation tile (fp32 -> bf16) into Xa: rows 0..127, cols 0..127
    for (int idx = tid; idx < 128 * 32; idx += 512) {
        int c4  = idx & 31;    // float4 index within row
        int row = idx >> 5;
        float4 v = *reinterpret_cast<const float4*>(obs + (long)(bbase + row) * OBS_ + c4 * 4);
        uint2 pk;
        pk.x = (unsigned)f2bf(v.x) | ((unsigned)f2bf(v.y) << 16);
        pk.y = (unsigned)f2bf(v.z) | ((unsigned)f2bf(v.w) << 16);
        *reinterpret_cast<uint2*>(Xa + row * XSTRIDE + c4 * 4) = pk;
    }
    // (first chunk's staging barrier covers visibility of Xa)

    layer_fwd<16, 4, true,  false>(Xa, Xb, Wt, W1, b1, g1, be1, p, tid, wave, ln, q, nullptr, 0);
    layer_fwd<16, 8, true,  false>(Xb, Xa, Wt, W2, b2, g2, be2, p, tid, wave, ln, q, nullptr, 0);
    layer_fwd<16, 8, true,  false>(Xa, Xb, Wt, W3, b3, g3, be3, p, tid, wave, ln, q, nullptr, 0);
    layer_fwd<2,  8, false, true >(Xb, Xa, Wt, W4, b4, g4, be4, p, tid, wave, ln, q, out, bbase);
}

extern "C" void kernel_launch(void* const* d_in, const int* in_sizes, int n_in,
                              void* d_out, int out_size, void* d_ws, size_t ws_size,
                              hipStream_t stream)
{
    const float* obs = (const float*)d_in[0];
    const float* W1  = (const float*)d_in[1];
    const float* b1  = (const float*)d_in[2];
    const float* g1  = (const float*)d_in[3];
    const float* be1 = (const float*)d_in[4];
    const float* W2  = (const float*)d_in[5];
    const float* b2  = (const float*)d_in[6];
    const float* g2  = (const float*)d_in[7];
    const float* be2 = (const float*)d_in[8];
    const float* W3  = (const float*)d_in[9];
    const float* b3  = (const float*)d_in[10];
    const float* g3  = (const float*)d_in[11];
    const float* be3 = (const float*)d_in[12];
    const float* W4  = (const float*)d_in[13];
    const float* b4  = (const float*)d_in[14];
    const float* g4  = (const float*)d_in[15];
    const float* be4 = (const float*)d_in[16];
    float* out = (float*)d_out;

    hipLaunchKernelGGL(policy_fused, dim3(2048), dim3(512), 0, stream,
                       obs, W1, b1, g1, be1, W2, b2, g2, be2,
                       W3, b3, g3, be3, W4, b4, g4, be4, out);
}

// Round 2
// 430.886 us; speedup vs baseline: 2.1410x; 2.1410x over previous
//
#include <hip/hip_runtime.h>

#define B_    4096
#define P_    64
#define OBS_  128
#define HID_  256
#define ACTD_ 32

typedef __attribute__((ext_vector_type(8)))  __bf16 bf16x8;
typedef __attribute__((ext_vector_type(4)))  float  f32x4;
typedef __attribute__((ext_vector_type(16))) float  f32x16;

#define XSTRIDE 264   // bf16 elems; 33 16B-units/row -> odd mod 8 -> bank-balanced A reads

// ws layout (bf16 elems):
//   L1 @ 0        : 64 * 128*256 = 2,097,152
//   L2 @ 2097152  : 64 * 256*256 = 4,194,304
//   L3 @ 6291456  : 64 * 256*256 = 4,194,304
//   L4 @ 10485760 : 64 * 256*32  =   524,288
#define WS1 0L
#define WS2 2097152L
#define WS3 6291456L
#define WS4 10485760L

__device__ __forceinline__ unsigned short f2bf(float x) {
    unsigned u = __builtin_bit_cast(unsigned, x);
    u = (u + 0x7fffu + ((u >> 16) & 1u)) >> 16;   // RNE
    return (unsigned short)u;
}

// -------- weight prep: fp32 [P][K][N] -> bf16 [P][K/32][4 u][N][8 j] --------
// This is byte-for-byte the LDS image the main kernel stages with
// global_load_lds (wave-uniform base + lane*16 -> must be contiguous).
template<int K, int N>
__global__ __launch_bounds__(256) void prep_w(const float* __restrict__ W,
                                              unsigned short* __restrict__ out)
{
    constexpr int CH = K / 32;
    int tid = blockIdx.x * 256 + threadIdx.x;
    int n    = tid % N;
    int rest = tid / N;
    int u    = rest % 4;
    rest    /= 4;
    int c    = rest % CH;
    int p    = rest / CH;
    const float* src = W + ((long)(p * K + c * 32 + u * 8)) * N + n;   // lane-consecutive n: coalesced
    unsigned short tmp[8];
#pragma unroll
    for (int j = 0; j < 8; ++j) tmp[j] = f2bf(src[(long)j * N]);
    unsigned short* dst = out + ((((long)(p * CH + c) * 4 + u) * N + n) * 8);
    *reinterpret_cast<uint4*>(dst) = *reinterpret_cast<const uint4*>(tmp);   // 16B coalesced
}

// -------- async global->LDS staging: nbytes contiguous, 16B/lane --------
__device__ __forceinline__ void stage(char* lds, const char* src, int nbytes, int tid)
{
    const int lnoff = (tid & 63) * 16;
    const int off   = (tid >> 6) * 1024 + lnoff;
    for (int i = off; i < nbytes; i += 4096) {   // wave-uniform trip count (lnoff < 1024)
        __builtin_amdgcn_global_load_lds(
            (const __attribute__((address_space(1))) unsigned int*)(const void*)(src + i),
            (__attribute__((address_space(3))) unsigned int*)(void*)(lds + (i - lnoff)),
            16, 0, 0);
    }
}

// -------- one 256-wide fused layer (32x32x16 MFMA, 2x2 tiles/wave) --------
template<int KCH>
__device__ __forceinline__ void layer256(
    unsigned short* __restrict__ X,
    char* __restrict__ Wb0, char* __restrict__ Wb1,
    const char* __restrict__ wsrc,
    const char* __restrict__ nsrc, int nbytes,
    const float* __restrict__ bp, const float* __restrict__ gp, const float* __restrict__ bep,
    float2* __restrict__ part, float2* __restrict__ stats,
    int tid, bool elu)
{
    const int w  = tid >> 6;         // wave 0..3 -> col stripe 64w..64w+63
    const int l5 = tid & 31;
    const int h  = (tid & 63) >> 5;  // lane half

    f32x16 acc[2][2];
#pragma unroll
    for (int rt = 0; rt < 2; ++rt)
#pragma unroll
        for (int ct = 0; ct < 2; ++ct)
#pragma unroll
            for (int r = 0; r < 16; ++r) acc[rt][ct][r] = 0.f;

    for (int c = 0; c < KCH; ++c) {
        // prefetch chunk c+1 (or next layer's chunk 0) into the other buffer
        const char* nx = (c + 1 < KCH) ? (wsrc + (long)(c + 1) * 16384) : nsrc;
        int nb         = (c + 1 < KCH) ? 16384 : nbytes;
        stage((c & 1) ? Wb0 : Wb1, nx, nb, tid);

        const char* wc = (c & 1) ? Wb1 : Wb0;
#pragma unroll
        for (int ks = 0; ks < 2; ++ks) {
            const int k0 = c * 32 + ks * 16 + h * 8;
            bf16x8 a0 = *(const bf16x8*)(X + l5 * XSTRIDE + k0);
            bf16x8 a1 = *(const bf16x8*)(X + (32 + l5) * XSTRIDE + k0);
            const char* bb = wc + (ks * 2 + h) * 4096;    // k-octet u = ks*2+h
            bf16x8 b0 = *(const bf16x8*)(bb + (w * 64 + l5) * 16);
            bf16x8 b1 = *(const bf16x8*)(bb + (w * 64 + 32 + l5) * 16);
            acc[0][0] = __builtin_amdgcn_mfma_f32_32x32x16_bf16(a0, b0, acc[0][0], 0, 0, 0);
            acc[1][0] = __builtin_amdgcn_mfma_f32_32x32x16_bf16(a1, b0, acc[1][0], 0, 0, 0);
            acc[0][1] = __builtin_amdgcn_mfma_f32_32x32x16_bf16(a0, b1, acc[0][1], 0, 0, 0);
            acc[1][1] = __builtin_amdgcn_mfma_f32_32x32x16_bf16(a1, b1, acc[1][1], 0, 0, 0);
        }
        __syncthreads();   // drains prefetch (vmcnt) + protects buffer reuse + last-chunk A-reads
    }

    // ---- epilogue: bias, GroupNorm over 256, optional ELU, in-place X update ----
    const int n0 = w * 64 + l5, n1 = n0 + 32;
    const float bb0 = bp[n0], bb1 = bp[n1];
#pragma unroll
    for (int rt = 0; rt < 2; ++rt)
#pragma unroll
        for (int r = 0; r < 16; ++r) { acc[rt][0][r] += bb0; acc[rt][1][r] += bb1; }

    // pass 1: write y (bf16) to X (safe: chunk-loop's final barrier covers in-place hazard)
#pragma unroll
    for (int rt = 0; rt < 2; ++rt)
#pragma unroll
        for (int r = 0; r < 16; ++r) {
            const int row = rt * 32 + (r & 3) + 8 * (r >> 2) + 4 * h;
            X[row * XSTRIDE + n0] = f2bf(acc[rt][0][r]);
            X[row * XSTRIDE + n1] = f2bf(acc[rt][1][r]);
        }
    __syncthreads();

    // pass 2: per-row (s, s2): wave w sums its 64-col stripe of row `lane`
    {
        const int lane = tid & 63;
        float s = 0.f, s2 = 0.f;
#pragma unroll
        for (int j8 = 0; j8 < 8; ++j8) {
            bf16x8 v8 = *(const bf16x8*)(X + lane * XSTRIDE + w * 64 + j8 * 8);
#pragma unroll
            for (int e = 0; e < 8; ++e) { float v = (float)v8[e]; s += v; s2 = fmaf(v, v, s2); }
        }
        part[lane * 4 + w] = make_float2(s, s2);
    }
    __syncthreads();
    if (w == 0) {
        const int lane = tid & 63;
        float2 p0 = part[lane * 4 + 0], p1 = part[lane * 4 + 1];
        float2 p2 = part[lane * 4 + 2], p3 = part[lane * 4 + 3];
        float s  = p0.x + p1.x + p2.x + p3.x;
        float s2 = p0.y + p1.y + p2.y + p3.y;
        float mu  = s * (1.f / 256.f);
        float var = s2 * (1.f / 256.f) - mu * mu;
        stats[lane] = make_float2(mu, rsqrtf(var + 1e-5f));
    }
    __syncthreads();

    const float g0 = gp[n0], g1 = gp[n1], be0 = bep[n0], be1 = bep[n1];
#pragma unroll
    for (int rt = 0; rt < 2; ++rt)
#pragma unroll
        for (int r = 0; r < 16; ++r) {
            const int row = rt * 32 + (r & 3) + 8 * (r >> 2) + 4 * h;
            float2 st = stats[row];                  // LDS broadcast
            float v0 = (acc[rt][0][r] - st.x) * st.y * g0 + be0;
            float v1 = (acc[rt][1][r] - st.x) * st.y * g1 + be1;
            if (elu) { v0 = (v0 > 0.f) ? v0 : expm1f(v0); v1 = (v1 > 0.f) ? v1 : expm1f(v1); }
            X[row * XSTRIDE + n0] = f2bf(v0);
            X[row * XSTRIDE + n1] = f2bf(v1);
        }
    __syncthreads();
}

// -------- final layer: N=32, 16x16x32 MFMA, GN via butterfly, fp32 out --------
__device__ __forceinline__ void layer32(
    const unsigned short* __restrict__ X,
    char* __restrict__ Wb0, char* __restrict__ Wb1,
    const char* __restrict__ wsrc,
    const float* __restrict__ bp, const float* __restrict__ gp, const float* __restrict__ bep,
    float* __restrict__ outg, int bbase, int p, int tid)
{
    const int w = tid >> 6, lane = tid & 63, ln = lane & 15, quad = lane >> 4;
    f32x4 acc[2];
#pragma unroll
    for (int nt = 0; nt < 2; ++nt)
#pragma unroll
        for (int r = 0; r < 4; ++r) acc[nt][r] = 0.f;

    for (int c = 0; c < 8; ++c) {
        if (c < 7) stage((c & 1) ? Wb0 : Wb1, wsrc + (long)(c + 1) * 2048, 2048, tid);
        const char* wc = (c & 1) ? Wb1 : Wb0;
        bf16x8 a  = *(const bf16x8*)(X + (16 * w + ln) * XSTRIDE + c * 32 + quad * 8);
        bf16x8 b0 = *(const bf16x8*)(wc + quad * 512 + ln * 16);
        bf16x8 b1 = *(const bf16x8*)(wc + quad * 512 + (16 + ln) * 16);
        acc[0] = __builtin_amdgcn_mfma_f32_16x16x32_bf16(a, b0, acc[0], 0, 0, 0);
        acc[1] = __builtin_amdgcn_mfma_f32_16x16x32_bf16(a, b1, acc[1], 0, 0, 0);
        __syncthreads();
    }

    const float bb0 = bp[ln], bb1 = bp[16 + ln];
    const float g0 = gp[ln], g1 = gp[16 + ln], be0 = bep[ln], be1 = bep[16 + ln];
#pragma unroll
    for (int r = 0; r < 4; ++r) {
        float y0 = acc[0][r] + bb0, y1 = acc[1][r] + bb1;
        float s = y0 + y1, s2 = y0 * y0 + y1 * y1;
        s += __shfl_xor(s, 1);  s2 += __shfl_xor(s2, 1);
        s += __shfl_xor(s, 2);  s2 += __shfl_xor(s2, 2);
        s += __shfl_xor(s, 4);  s2 += __shfl_xor(s2, 4);
        s += __shfl_xor(s, 8);  s2 += __shfl_xor(s2, 8);
        float mu  = s * (1.f / 32.f);
        float var = s2 * (1.f / 32.f) - mu * mu;
        float rs  = rsqrtf(var + 1e-5f);
        const int row = bbase + 16 * w + quad * 4 + r;
        float* o = outg + ((long)row * P_ + p) * ACTD_;
        o[ln]      = (y0 - mu) * rs * g0 + be0;
        o[16 + ln] = (y1 - mu) * rs * g1 + be1;
    }
}

extern "C" __global__ void __launch_bounds__(256, 2)
policy_fused(const float* __restrict__ obs,
             const unsigned short* __restrict__ wbf,
             const float* __restrict__ b1, const float* __restrict__ g1, const float* __restrict__ be1,
             const float* __restrict__ b2, const float* __restrict__ g2, const float* __restrict__ be2,
             const float* __restrict__ b3, const float* __restrict__ g3, const float* __restrict__ be3,
             const float* __restrict__ b4, const float* __restrict__ g4, const float* __restrict__ be4,
             float* __restrict__ out)
{
    __shared__ __align__(16) unsigned short X[64 * XSTRIDE];   // 33.8 KB, in-place activations
    __shared__ __align__(16) char Wbuf0[16384];
    __shared__ __align__(16) char Wbuf1[16384];
    __shared__ float2 part[64 * 4];
    __shared__ float2 stats[64];

    const int tid = threadIdx.x;
    const int bx  = blockIdx.x;
    // XCD-locality swizzle: all 64 batch-tiles of a policy share bx%64 -> same XCD slot;
    // 8 policies/XCD -> 2.75 MB bf16 weights, fits per-XCD L2.
    const int p     = ((bx & 7) << 3) | ((bx >> 3) & 7);
    const int bbase = (bx >> 6) * 64;

    const char* ws1 = (const char*)(wbf + WS1 + (long)p * (128 * 256));
    const char* ws2 = (const char*)(wbf + WS2 + (long)p * (256 * 256));
    const char* ws3 = (const char*)(wbf + WS3 + (long)p * (256 * 256));
    const char* ws4 = (const char*)(wbf + WS4 + (long)p * (256 * 32));

    stage(Wbuf0, ws1, 16384, tid);   // L1 chunk 0, overlaps obs staging

    // obs fp32 -> X bf16 (rows 0..63, cols 0..127)
    for (int idx = tid; idx < 64 * 32; idx += 256) {
        int row = idx >> 5, c4 = idx & 31;
        float4 v = *reinterpret_cast<const float4*>(obs + (long)(bbase + row) * OBS_ + c4 * 4);
        uint2 pk;
        pk.x = (unsigned)f2bf(v.x) | ((unsigned)f2bf(v.y) << 16);
        pk.y = (unsigned)f2bf(v.z) | ((unsigned)f2bf(v.w) << 16);
        *reinterpret_cast<uint2*>(X + row * XSTRIDE + c4 * 4) = pk;
    }
    __syncthreads();

    layer256<4>(X, Wbuf0, Wbuf1, ws1, ws2, 16384,
                b1 + p * 256, g1 + p * 256, be1 + p * 256, part, stats, tid, true);
    layer256<8>(X, Wbuf0, Wbuf1, ws2, ws3, 16384,
                b2 + p * 256, g2 + p * 256, be2 + p * 256, part, stats, tid, true);
    layer256<8>(X, Wbuf0, Wbuf1, ws3, ws4, 2048,
                b3 + p * 256, g3 + p * 256, be3 + p * 256, part, stats, tid, true);
    layer32(X, Wbuf0, Wbuf1, ws4,
            b4 + p * 32, g4 + p * 32, be4 + p * 32, out, bbase, p, tid);
}

extern "C" void kernel_launch(void* const* d_in, const int* in_sizes, int n_in,
                              void* d_out, int out_size, void* d_ws, size_t ws_size,
                              hipStream_t stream)
{
    const float* obs = (const float*)d_in[0];
    const float* W1  = (const float*)d_in[1];
    const float* b1  = (const float*)d_in[2];
    const float* g1  = (const float*)d_in[3];
    const float* be1 = (const float*)d_in[4];
    const float* W2  = (const float*)d_in[5];
    const float* b2  = (const float*)d_in[6];
    const float* g2  = (const float*)d_in[7];
    const float* be2 = (const float*)d_in[8];
    const float* W3  = (const float*)d_in[9];
    const float* b3  = (const float*)d_in[10];
    const float* g3  = (const float*)d_in[11];
    const float* be3 = (const float*)d_in[12];
    const float* W4  = (const float*)d_in[13];
    const float* b4  = (const float*)d_in[14];
    const float* g4  = (const float*)d_in[15];
    const float* be4 = (const float*)d_in[16];
    float* out = (float*)d_out;
    unsigned short* ws = (unsigned short*)d_ws;

    // weight conversion+relayout (bf16, MFMA-ready LDS images), every call (graph-safe)
    hipLaunchKernelGGL((prep_w<128, 256>), dim3(1024), dim3(256), 0, stream, W1, ws + WS1);
    hipLaunchKernelGGL((prep_w<256, 256>), dim3(2048), dim3(256), 0, stream, W2, ws + WS2);
    hipLaunchKernelGGL((prep_w<256, 256>), dim3(2048), dim3(256), 0, stream, W3, ws + WS3);
    hipLaunchKernelGGL((prep_w<256, 32>),  dim3(256),  dim3(256), 0, stream, W4, ws + WS4);

    hipLaunchKernelGGL(policy_fused, dim3(4096), dim3(256), 0, stream,
                       obs, ws,
                       b1, g1, be1, b2, g2, be2, b3, g3, be3, b4, g4, be4, out);
}